// Round 3
// baseline (150.044 us; speedup 1.0000x reference)
//
#include <hip/hip_runtime.h>
#include <math.h>

namespace {
constexpr int kS = 1024;                       // row length (fixed by problem)
constexpr float kEps = 1e-8f;
constexpr float kNegLogEps = 18.420680743952367f;     // -log(1e-8)
constexpr float kMaxEntropy = 6.9314718055994531f;    // log(1024)
constexpr float kInvMaxEntropy = 1.0f / 6.9314718055994531f;
constexpr float kTargetEntropy = 4.8520302639196169f; // log(1024)*0.7
constexpr float kBaseMaskProb = 0.15f;
constexpr int kRowsPerWave = 8;
typedef float f32x4 __attribute__((ext_vector_type(4)));
}

// Process one row (1024 f32) held entirely in this wave's registers.
// All reductions are in-wave shfl_xor butterflies: no LDS, no barriers.
__device__ __forceinline__ void process_row(
    f32x4 a0, f32x4 a1, f32x4 a2, f32x4 a3,
    f32x4 b0, f32x4 b1, f32x4 b2, f32x4 b3,
    int row, int lane,
    float* __restrict__ out_w,
    float* __restrict__ out_ent,
    float* __restrict__ out_mrate,
    float* __restrict__ out_tent)
{
    float w[16];
    w[0]=a0.x;  w[1]=a0.y;  w[2]=a0.z;  w[3]=a0.w;
    w[4]=a1.x;  w[5]=a1.y;  w[6]=a1.z;  w[7]=a1.w;
    w[8]=a2.x;  w[9]=a2.y;  w[10]=a2.z; w[11]=a2.w;
    w[12]=a3.x; w[13]=a3.y; w[14]=a3.z; w[15]=a3.w;

    // ---- local sum + plogp over RAW weights (entropy = ln s - p/s) ----
    float s = 0.0f, p = 0.0f;
    #pragma unroll
    for (int i = 0; i < 16; ++i) {
        s += w[i];
        p += w[i] * __logf(fmaxf(w[i], 1e-37f));   // w==0 -> 0*finite = 0
    }
    #pragma unroll
    for (int o = 1; o < 64; o <<= 1) {
        s += __shfl_xor(s, o, 64);
        p += __shfl_xor(p, o, 64);
    }

    // degenerate row (sum < eps): uniform weights (wave-uniform, ~never)
    if (s < kEps) {
        #pragma unroll
        for (int i = 0; i < 16; ++i) w[i] = 1.0f / (float)kS;
        s = 1.0f;
        p = -kMaxEntropy;   // => entropy = ln(1024)
    }

    const float inv_s   = 1.0f / s;
    const float entropy = fminf(__logf(s) - p * inv_s, kNegLogEps);
    const float nent    = fminf(fmaxf(entropy * kInvMaxEntropy, 0.0f), 1.0f);
    const float keep    = 1.0f - kBaseMaskProb * (1.0f - nent);

    // ---- mask from noise; local count + masked raw-sum ----
    float nz[16];
    nz[0]=b0.x;  nz[1]=b0.y;  nz[2]=b0.z;  nz[3]=b0.w;
    nz[4]=b1.x;  nz[5]=b1.y;  nz[6]=b1.z;  nz[7]=b1.w;
    nz[8]=b2.x;  nz[9]=b2.y;  nz[10]=b2.z; nz[11]=b2.w;
    nz[12]=b3.x; nz[13]=b3.y; nz[14]=b3.z; nz[15]=b3.w;

    unsigned mask = 0u;
    float msum = 0.0f, cntf = 0.0f;
    #pragma unroll
    for (int i = 0; i < 16; ++i) {
        if (nz[i] < keep) { mask |= (1u << i); msum += w[i]; cntf += 1.0f; }
    }

    const unsigned long long anyk = __ballot(mask != 0u);

    #pragma unroll
    for (int o = 1; o < 64; o <<= 1) {
        cntf += __shfl_xor(cntf, o, 64);
        msum += __shfl_xor(msum, o, 64);
    }

    // ---- min_active fallback (only when NO element kept; ~never taken) ----
    if (anyk == 0ull) {
        float mxv = w[0];
        int   mxi = lane * 4;      // idx(i) = (i>>2)*256 + lane*4 + (i&3), monotone in i
        #pragma unroll
        for (int i = 1; i < 16; ++i) {
            const int idx = ((i >> 2) << 8) + lane * 4 + (i & 3);
            if (w[i] > mxv) { mxv = w[i]; mxi = idx; }
        }
        #pragma unroll
        for (int o = 1; o < 64; o <<= 1) {
            const float ov = __shfl_xor(mxv, o, 64);
            const int   oi = __shfl_xor(mxi, o, 64);
            if (ov > mxv || (ov == mxv && oi < mxi)) { mxv = ov; mxi = oi; }
        }
        mask = (((mxi >> 2) & 63) == lane) ? (1u << (((mxi >> 8) << 2) | (mxi & 3))) : 0u;
        msum = mxv;
        cntf = 1.0f;
    }

    // ---- renormalize: final = w_raw/msum_raw (the row-sum cancels) ----
    const bool  valid = msum > kEps * s;           // msum_norm > eps
    const float scale = valid ? 1.0f / msum : inv_s;

    f32x4 f0, f1, f2, f3;
    #pragma unroll
    for (int i = 0; i < 16; ++i) {
        const float v = (valid && !((mask >> i) & 1u)) ? 0.0f : w[i] * scale;
        f32x4* dstv = (i < 4) ? &f0 : (i < 8) ? &f1 : (i < 12) ? &f2 : &f3;
        (*dstv)[i & 3] = v;
    }

    f32x4* __restrict__ dst = reinterpret_cast<f32x4*>(out_w + ((long long)row << 10));
    __builtin_nontemporal_store(f0, dst + lane);
    __builtin_nontemporal_store(f1, dst + lane + 64);
    __builtin_nontemporal_store(f2, dst + lane + 128);
    __builtin_nontemporal_store(f3, dst + lane + 192);

    if (lane == 0) out_ent[row]   = entropy;
    if (lane == 1) out_mrate[row] = 1.0f - cntf * (1.0f / (float)kS);
    if (lane == 2) out_tent[row]  = kTargetEntropy;
}

// One wave per row, kRowsPerWave rows per wave, software-pipelined:
// the NEXT row's 8x global_load_dwordx4 are issued before the current row's
// compute tail, keeping every wave's loads in flight ~100% of its lifetime.
__global__ __launch_bounds__(256, 4)
void curriculum_kernel(const float* __restrict__ weights,
                       const float* __restrict__ noise,
                       float* __restrict__ out_w,
                       float* __restrict__ out_ent,
                       float* __restrict__ out_mrate,
                       float* __restrict__ out_tent,
                       int nrows, int wstride)
{
    const int lane = threadIdx.x & 63;
    int row = (blockIdx.x << 2) | (threadIdx.x >> 6);
    if (row >= nrows) return;

    const f32x4* __restrict__ ws = reinterpret_cast<const f32x4*>(weights + ((long long)row << 10));
    const f32x4* __restrict__ ns = reinterpret_cast<const f32x4*>(noise   + ((long long)row << 10));
    f32x4 a0 = ws[lane], a1 = ws[lane+64], a2 = ws[lane+128], a3 = ws[lane+192];
    f32x4 b0 = ns[lane], b1 = ns[lane+64], b2 = ns[lane+128], b3 = ns[lane+192];

    for (int k = 0; k < kRowsPerWave; ++k) {
        const int nrow = row + wstride;
        const bool pf = (k + 1 < kRowsPerWave) && (nrow < nrows);

        f32x4 na0, na1, na2, na3, nb0, nb1, nb2, nb3;
        if (pf) {
            const f32x4* nw = reinterpret_cast<const f32x4*>(weights + ((long long)nrow << 10));
            const f32x4* nn = reinterpret_cast<const f32x4*>(noise   + ((long long)nrow << 10));
            na0 = nw[lane]; na1 = nw[lane+64]; na2 = nw[lane+128]; na3 = nw[lane+192];
            nb0 = nn[lane]; nb1 = nn[lane+64]; nb2 = nn[lane+128]; nb3 = nn[lane+192];
        }

        process_row(a0, a1, a2, a3, b0, b1, b2, b3, row, lane,
                    out_w, out_ent, out_mrate, out_tent);

        if (!pf) break;
        row = nrow;
        a0 = na0; a1 = na1; a2 = na2; a3 = na3;
        b0 = nb0; b1 = nb1; b2 = nb2; b3 = nb3;
    }
}

extern "C" void kernel_launch(void* const* d_in, const int* in_sizes, int n_in,
                              void* d_out, int out_size, void* d_ws, size_t ws_size,
                              hipStream_t stream)
{
    (void)n_in; (void)d_ws; (void)ws_size; (void)out_size;

    const float* weights = (const float*)d_in[0];
    const float* noise   = (const float*)d_in[1];
    const long long total = (long long)in_sizes[0];   // B*H*S*S
    const int nrows = (int)(total / kS);              // B*H*S

    float* out_w     = (float*)d_out;                 // [B,H,S,S]
    float* out_ent   = out_w + total;                 // [B,H,S]
    float* out_mrate = out_ent + nrows;               // [B,H,S]
    float* out_tent  = out_mrate + nrows;             // [B,H,S]

    // 4 waves/block, kRowsPerWave rows per wave
    const int rows_per_block = 4 * kRowsPerWave;
    const int blocks = (nrows + rows_per_block - 1) / rows_per_block;
    const int wstride = blocks * 4;                   // total waves in grid

    hipLaunchKernelGGL(curriculum_kernel, dim3(blocks), dim3(256), 0, stream,
                       weights, noise, out_w, out_ent, out_mrate, out_tent,
                       nrows, wstride);
}

// Round 4
// 142.601 us; speedup vs baseline: 1.0522x; 1.0522x over previous
//
#include <hip/hip_runtime.h>
#include <math.h>

namespace {
constexpr int kS = 1024;                       // row length (fixed by problem)
constexpr float kEps = 1e-8f;
constexpr float kNegLogEps = 18.420680743952367f;     // -log(1e-8)
constexpr float kMaxEntropy = 6.9314718055994531f;    // log(1024)
constexpr float kInvMaxEntropy = 1.0f / 6.9314718055994531f;
constexpr float kTargetEntropy = 4.8520302639196169f; // log(1024)*0.7
constexpr float kBaseMaskProb = 0.15f;
typedef float f32x4 __attribute__((ext_vector_type(4)));
}

// One wave (64 lanes) per row of 1024 f32; 4 rows per 256-thread block.
// All 8 input loads (weights + noise) are issued upfront and PINNED with an
// asm-liveness barrier so the compiler cannot sink them (R2/R3 post-mortem:
// VGPR_Count 28/48 proved the "prefetch" loads were being sunk to their uses,
// leaving per-wave MLP at ~2 instead of 8).
__global__ __launch_bounds__(256, 8)
void curriculum_kernel(const float* __restrict__ weights,
                       const float* __restrict__ noise,
                       float* __restrict__ out_w,
                       float* __restrict__ out_ent,
                       float* __restrict__ out_mrate,
                       float* __restrict__ out_tent,
                       int nrows)
{
    const int lane = threadIdx.x & 63;
    const int row  = (blockIdx.x << 2) | (threadIdx.x >> 6);
    if (row >= nrows) return;

    const long long base = (long long)row << 10;
    const f32x4* __restrict__ wsrc = reinterpret_cast<const f32x4*>(weights + base);
    const f32x4* __restrict__ nsrc = reinterpret_cast<const f32x4*>(noise + base);

    // ---- issue ALL 8 global_load_dwordx4, then pin them (no sinking) ----
    f32x4 a0 = wsrc[lane];
    f32x4 a1 = wsrc[lane + 64];
    f32x4 a2 = wsrc[lane + 128];
    f32x4 a3 = wsrc[lane + 192];
    f32x4 b0 = nsrc[lane];
    f32x4 b1 = nsrc[lane + 64];
    f32x4 b2 = nsrc[lane + 128];
    f32x4 b3 = nsrc[lane + 192];
    asm volatile("" :: "v"(a0), "v"(a1), "v"(a2), "v"(a3),
                       "v"(b0), "v"(b1), "v"(b2), "v"(b3));

    float w[16];
    w[0]=a0.x;  w[1]=a0.y;  w[2]=a0.z;  w[3]=a0.w;
    w[4]=a1.x;  w[5]=a1.y;  w[6]=a1.z;  w[7]=a1.w;
    w[8]=a2.x;  w[9]=a2.y;  w[10]=a2.z; w[11]=a2.w;
    w[12]=a3.x; w[13]=a3.y; w[14]=a3.z; w[15]=a3.w;

    // ---- local sum + plogp over RAW weights (entropy = ln s - p/s) ----
    float s = 0.0f, p = 0.0f;
    #pragma unroll
    for (int i = 0; i < 16; ++i) {
        s += w[i];
        p += w[i] * __logf(fmaxf(w[i], 1e-37f));   // w==0 -> 0*finite = 0
    }
    #pragma unroll
    for (int o = 1; o < 64; o <<= 1) {
        s += __shfl_xor(s, o, 64);
        p += __shfl_xor(p, o, 64);
    }

    // degenerate row (sum < eps): uniform weights (wave-uniform, ~never)
    if (s < kEps) {
        #pragma unroll
        for (int i = 0; i < 16; ++i) w[i] = 1.0f / (float)kS;
        s = 1.0f;
        p = -kMaxEntropy;   // => entropy = ln(1024)
    }

    const float inv_s   = 1.0f / s;
    const float entropy = fminf(__logf(s) - p * inv_s, kNegLogEps);
    const float nent    = fminf(fmaxf(entropy * kInvMaxEntropy, 0.0f), 1.0f);
    const float keep    = 1.0f - kBaseMaskProb * (1.0f - nent);

    // ---- mask from noise; local count + masked raw-sum ----
    float nz[16];
    nz[0]=b0.x;  nz[1]=b0.y;  nz[2]=b0.z;  nz[3]=b0.w;
    nz[4]=b1.x;  nz[5]=b1.y;  nz[6]=b1.z;  nz[7]=b1.w;
    nz[8]=b2.x;  nz[9]=b2.y;  nz[10]=b2.z; nz[11]=b2.w;
    nz[12]=b3.x; nz[13]=b3.y; nz[14]=b3.z; nz[15]=b3.w;

    unsigned mask = 0u;
    float msum = 0.0f, cntf = 0.0f;
    #pragma unroll
    for (int i = 0; i < 16; ++i) {
        if (nz[i] < keep) { mask |= (1u << i); msum += w[i]; cntf += 1.0f; }
    }

    const unsigned long long anyk = __ballot(mask != 0u);

    #pragma unroll
    for (int o = 1; o < 64; o <<= 1) {
        cntf += __shfl_xor(cntf, o, 64);
        msum += __shfl_xor(msum, o, 64);
    }

    // ---- min_active fallback (only when NO element kept; ~never taken) ----
    if (anyk == 0ull) {
        float mxv = w[0];
        int   mxi = lane * 4;      // idx(i) = (i>>2)*256 + lane*4 + (i&3), monotone in i
        #pragma unroll
        for (int i = 1; i < 16; ++i) {
            const int idx = ((i >> 2) << 8) + lane * 4 + (i & 3);
            if (w[i] > mxv) { mxv = w[i]; mxi = idx; }
        }
        #pragma unroll
        for (int o = 1; o < 64; o <<= 1) {
            const float ov = __shfl_xor(mxv, o, 64);
            const int   oi = __shfl_xor(mxi, o, 64);
            if (ov > mxv || (ov == mxv && oi < mxi)) { mxv = ov; mxi = oi; }
        }
        mask = (((mxi >> 2) & 63) == lane) ? (1u << (((mxi >> 8) << 2) | (mxi & 3))) : 0u;
        msum = mxv;
        cntf = 1.0f;
    }

    // ---- renormalize: final = w_raw/msum_raw (the row-sum cancels) ----
    const bool  valid = msum > kEps * s;           // msum_norm > eps
    const float scale = valid ? 1.0f / msum : inv_s;

    f32x4 f0, f1, f2, f3;
    #pragma unroll
    for (int i = 0; i < 16; ++i) {
        const float v = (valid && !((mask >> i) & 1u)) ? 0.0f : w[i] * scale;
        f32x4* dstv = (i < 4) ? &f0 : (i < 8) ? &f1 : (i < 12) ? &f2 : &f3;
        (*dstv)[i & 3] = v;
    }

    f32x4* __restrict__ dst = reinterpret_cast<f32x4*>(out_w + base);
    __builtin_nontemporal_store(f0, dst + lane);
    __builtin_nontemporal_store(f1, dst + lane + 64);
    __builtin_nontemporal_store(f2, dst + lane + 128);
    __builtin_nontemporal_store(f3, dst + lane + 192);

    if (lane == 0) out_ent[row]   = entropy;
    if (lane == 1) out_mrate[row] = 1.0f - cntf * (1.0f / (float)kS);
    if (lane == 2) out_tent[row]  = kTargetEntropy;
}

extern "C" void kernel_launch(void* const* d_in, const int* in_sizes, int n_in,
                              void* d_out, int out_size, void* d_ws, size_t ws_size,
                              hipStream_t stream)
{
    (void)n_in; (void)d_ws; (void)ws_size; (void)out_size;

    const float* weights = (const float*)d_in[0];
    const float* noise   = (const float*)d_in[1];
    const long long total = (long long)in_sizes[0];   // B*H*S*S
    const int nrows = (int)(total / kS);              // B*H*S

    float* out_w     = (float*)d_out;                 // [B,H,S,S]
    float* out_ent   = out_w + total;                 // [B,H,S]
    float* out_mrate = out_ent + nrows;               // [B,H,S]
    float* out_tent  = out_mrate + nrows;             // [B,H,S]

    const int blocks = (nrows + 3) / 4;               // 4 rows (waves) per block
    hipLaunchKernelGGL(curriculum_kernel, dim3(blocks), dim3(256), 0, stream,
                       weights, noise, out_w, out_ent, out_mrate, out_tent, nrows);
}

// Round 5
// 142.506 us; speedup vs baseline: 1.0529x; 1.0007x over previous
//
#include <hip/hip_runtime.h>
#include <math.h>

namespace {
constexpr int kS = 1024;                       // row length (fixed by problem)
constexpr float kEps = 1e-8f;
constexpr float kNegLogEps = 18.420680743952367f;     // -log(1e-8)
constexpr float kMaxEntropy = 6.9314718055994531f;    // log(1024)
constexpr float kInvMaxEntropy = 1.0f / 6.9314718055994531f;
constexpr float kTargetEntropy = 4.8520302639196169f; // log(1024)*0.7
constexpr float kBaseMaskProb = 0.15f;
typedef float f32x4 __attribute__((ext_vector_type(4)));
typedef __attribute__((address_space(1))) const void gas_t;
typedef __attribute__((address_space(3))) void las_t;
}

// One wave (64 lanes) per row of 1024 f32; 4 rows per 256-thread block.
// R5 structure: weights staged global->LDS via global_load_lds DMA (exactly-once
// global read, zero VGPR, cannot be sunk or duplicated by the compiler -- the
// R2-R4 post-mortems showed VGPR_Count=28, i.e. the allocator kept re-reading
// operands from L2 instead of keeping them resident). noise goes to registers
// (single use). Compute re-reads of w now hit LDS (~12cy) instead of L2.
__global__ __launch_bounds__(256, 8)
void curriculum_kernel(const float* __restrict__ weights,
                       const float* __restrict__ noise,
                       float* __restrict__ out_w,
                       float* __restrict__ out_ent,
                       float* __restrict__ out_mrate,
                       float* __restrict__ out_tent,
                       int nrows)
{
    __shared__ float lds_w[4][kS];            // 16 KB/block, one row per wave

    const int lane = threadIdx.x & 63;
    const int wid  = threadIdx.x >> 6;
    const int row  = (blockIdx.x << 2) | wid;
    if (row >= nrows) return;

    const long long base = (long long)row << 10;
    const float* __restrict__ wrow = weights + base;
    const f32x4* __restrict__ nsrc = reinterpret_cast<const f32x4*>(noise + base);

    // ---- issue 4x global_load_lds DMA for the weights row (fire-and-forget) ----
    // HW writes lane L's 16B at lds_base + L*16: layout matches the global row.
    {
        float* l0 = &lds_w[wid][0];
        const float* g0 = wrow + (lane << 2);
        __builtin_amdgcn_global_load_lds((gas_t*)(g0),        (las_t*)(l0),        16, 0, 0);
        __builtin_amdgcn_global_load_lds((gas_t*)(g0 + 256),  (las_t*)(l0 + 256),  16, 0, 0);
        __builtin_amdgcn_global_load_lds((gas_t*)(g0 + 512),  (las_t*)(l0 + 512),  16, 0, 0);
        __builtin_amdgcn_global_load_lds((gas_t*)(g0 + 768),  (las_t*)(l0 + 768),  16, 0, 0);
    }

    // ---- noise row -> registers (single use later; issued before the wait) ----
    f32x4 b0 = nsrc[lane];
    f32x4 b1 = nsrc[lane + 64];
    f32x4 b2 = nsrc[lane + 128];
    f32x4 b3 = nsrc[lane + 192];

    // wait for the LDS DMA (and the nz loads) -- per-wave, no barrier needed
    asm volatile("s_waitcnt vmcnt(0)" ::: "memory");

    // ---- read w from LDS (ds_read_b128, 2-way bank alias = free) ----
    const f32x4* __restrict__ lw = reinterpret_cast<const f32x4*>(&lds_w[wid][0]);
    f32x4 a0 = lw[lane];
    f32x4 a1 = lw[lane + 64];
    f32x4 a2 = lw[lane + 128];
    f32x4 a3 = lw[lane + 192];

    float w[16];
    w[0]=a0.x;  w[1]=a0.y;  w[2]=a0.z;  w[3]=a0.w;
    w[4]=a1.x;  w[5]=a1.y;  w[6]=a1.z;  w[7]=a1.w;
    w[8]=a2.x;  w[9]=a2.y;  w[10]=a2.z; w[11]=a2.w;
    w[12]=a3.x; w[13]=a3.y; w[14]=a3.z; w[15]=a3.w;

    // ---- local sum + plogp over RAW weights (entropy = ln s - p/s) ----
    float s = 0.0f, p = 0.0f;
    #pragma unroll
    for (int i = 0; i < 16; ++i) {
        s += w[i];
        p += w[i] * __logf(fmaxf(w[i], 1e-37f));   // w==0 -> 0*finite = 0
    }
    #pragma unroll
    for (int o = 1; o < 64; o <<= 1) {
        s += __shfl_xor(s, o, 64);
        p += __shfl_xor(p, o, 64);
    }

    // degenerate row (sum < eps): uniform weights (wave-uniform, ~never)
    if (s < kEps) {
        #pragma unroll
        for (int i = 0; i < 16; ++i) w[i] = 1.0f / (float)kS;
        s = 1.0f;
        p = -kMaxEntropy;   // => entropy = ln(1024)
    }

    const float inv_s   = 1.0f / s;
    const float entropy = fminf(__logf(s) - p * inv_s, kNegLogEps);
    const float nent    = fminf(fmaxf(entropy * kInvMaxEntropy, 0.0f), 1.0f);
    const float keep    = 1.0f - kBaseMaskProb * (1.0f - nent);

    // ---- mask from noise; local count + masked raw-sum ----
    float nz[16];
    nz[0]=b0.x;  nz[1]=b0.y;  nz[2]=b0.z;  nz[3]=b0.w;
    nz[4]=b1.x;  nz[5]=b1.y;  nz[6]=b1.z;  nz[7]=b1.w;
    nz[8]=b2.x;  nz[9]=b2.y;  nz[10]=b2.z; nz[11]=b2.w;
    nz[12]=b3.x; nz[13]=b3.y; nz[14]=b3.z; nz[15]=b3.w;

    unsigned mask = 0u;
    float msum = 0.0f, cntf = 0.0f;
    #pragma unroll
    for (int i = 0; i < 16; ++i) {
        if (nz[i] < keep) { mask |= (1u << i); msum += w[i]; cntf += 1.0f; }
    }

    const unsigned long long anyk = __ballot(mask != 0u);

    #pragma unroll
    for (int o = 1; o < 64; o <<= 1) {
        cntf += __shfl_xor(cntf, o, 64);
        msum += __shfl_xor(msum, o, 64);
    }

    // ---- min_active fallback (only when NO element kept; ~never taken) ----
    if (anyk == 0ull) {
        float mxv = w[0];
        int   mxi = lane * 4;      // idx(i) = (i>>2)*256 + lane*4 + (i&3), monotone in i
        #pragma unroll
        for (int i = 1; i < 16; ++i) {
            const int idx = ((i >> 2) << 8) + lane * 4 + (i & 3);
            if (w[i] > mxv) { mxv = w[i]; mxi = idx; }
        }
        #pragma unroll
        for (int o = 1; o < 64; o <<= 1) {
            const float ov = __shfl_xor(mxv, o, 64);
            const int   oi = __shfl_xor(mxi, o, 64);
            if (ov > mxv || (ov == mxv && oi < mxi)) { mxv = ov; mxi = oi; }
        }
        mask = (((mxi >> 2) & 63) == lane) ? (1u << (((mxi >> 8) << 2) | (mxi & 3))) : 0u;
        msum = mxv;
        cntf = 1.0f;
    }

    // ---- renormalize: final = w_raw/msum_raw (the row-sum cancels) ----
    const bool  valid = msum > kEps * s;           // msum_norm > eps
    const float scale = valid ? 1.0f / msum : inv_s;

    f32x4 f0, f1, f2, f3;
    #pragma unroll
    for (int i = 0; i < 16; ++i) {
        const float v = (valid && !((mask >> i) & 1u)) ? 0.0f : w[i] * scale;
        f32x4* dstv = (i < 4) ? &f0 : (i < 8) ? &f1 : (i < 12) ? &f2 : &f3;
        (*dstv)[i & 3] = v;
    }

    f32x4* __restrict__ dst = reinterpret_cast<f32x4*>(out_w + base);
    __builtin_nontemporal_store(f0, dst + lane);
    __builtin_nontemporal_store(f1, dst + lane + 64);
    __builtin_nontemporal_store(f2, dst + lane + 128);
    __builtin_nontemporal_store(f3, dst + lane + 192);

    if (lane == 0) out_ent[row]   = entropy;
    if (lane == 1) out_mrate[row] = 1.0f - cntf * (1.0f / (float)kS);
    if (lane == 2) out_tent[row]  = kTargetEntropy;
}

extern "C" void kernel_launch(void* const* d_in, const int* in_sizes, int n_in,
                              void* d_out, int out_size, void* d_ws, size_t ws_size,
                              hipStream_t stream)
{
    (void)n_in; (void)d_ws; (void)ws_size; (void)out_size;

    const float* weights = (const float*)d_in[0];
    const float* noise   = (const float*)d_in[1];
    const long long total = (long long)in_sizes[0];   // B*H*S*S
    const int nrows = (int)(total / kS);              // B*H*S

    float* out_w     = (float*)d_out;                 // [B,H,S,S]
    float* out_ent   = out_w + total;                 // [B,H,S]
    float* out_mrate = out_ent + nrows;               // [B,H,S]
    float* out_tent  = out_mrate + nrows;             // [B,H,S]

    const int blocks = (nrows + 3) / 4;               // 4 rows (waves) per block
    hipLaunchKernelGGL(curriculum_kernel, dim3(blocks), dim3(256), 0, stream,
                       weights, noise, out_w, out_ent, out_mrate, out_tent, nrows);
}